// Round 6
// baseline (223.595 us; speedup 1.0000x reference)
//
#include <hip/hip_runtime.h>
#include <math.h>

#define NTOK 2304      // 48*48 tokens
#define BATCH 2
#define CIN 256
#define HID 512        // 8 heads * 64
#define NH 8
#define LOG2E 1.44269504088896340736f

typedef __attribute__((ext_vector_type(8))) short bfrag;    // 8 bf16 (4 VGPRs)
typedef __attribute__((ext_vector_type(16))) float f32x16;  // MFMA 32x32 accumulator

#if __has_builtin(__builtin_amdgcn_exp2f)
#define EXP2(x) __builtin_amdgcn_exp2f(x)
#else
#define EXP2(x) exp2f(x)
#endif

// fp32 -> bf16 (RNE)
__device__ __forceinline__ unsigned f2bf(float f) {
    unsigned u = __float_as_uint(f);
    u += 0x7FFF + ((u >> 16) & 1);
    return u >> 16;
}

// pack trunc(hi(b)) , trunc(hi(a)) -> one dword {bf16(b):bf16(a)} in 1 v_perm
__device__ __forceinline__ unsigned pk_trunc(float a, float b) {
    return __builtin_amdgcn_perm(__float_as_uint(b), __float_as_uint(a), 0x07060302u);
}

// ---------------------------------------------------------------------------
// Pack both weight matrices fp32 -> bf16 in one dispatch.
// ---------------------------------------------------------------------------
__global__ __launch_bounds__(256) void pack_weights(
    const float* __restrict__ wq, short* __restrict__ wqb,
    const float* __restrict__ wp, short* __restrict__ wpb)
{
    int e = (blockIdx.x * 256 + threadIdx.x) * 8;
    const int NQ = 1536 * 256;
    const float* src; short* dst;
    if (e < NQ) { src = wq + e; dst = wqb + e; }
    else        { src = wp + (e - NQ); dst = wpb + (e - NQ); }
    float4 v0 = ((const float4*)src)[0];
    float4 v1 = ((const float4*)src)[1];
    unsigned b0 = f2bf(v0.x) | (f2bf(v0.y) << 16);
    unsigned b1 = f2bf(v0.z) | (f2bf(v0.w) << 16);
    unsigned b2 = f2bf(v1.x) | (f2bf(v1.y) << 16);
    unsigned b3 = f2bf(v1.z) | (f2bf(v1.w) << 16);
    *((uint4*)dst) = make_uint4(b0, b1, b2, b3);
}

// ---------------------------------------------------------------------------
// Transpose-pack x: fp32 [b][256][2304] -> bf16 xT [b][2304][256]
// ---------------------------------------------------------------------------
__global__ __launch_bounds__(256) void pack_xT(
    const float* __restrict__ x, short* __restrict__ xT)
{
    int n0 = blockIdx.x * 64, c0 = blockIdx.y * 64, b = blockIdx.z;
    __shared__ float sT[64][65];
    int tid = threadIdx.x, lane = tid & 63, wv = tid >> 6;
    for (int c = wv; c < 64; c += 4)
        sT[c][lane] = x[((size_t)b * CIN + c0 + c) * NTOK + n0 + lane];
    __syncthreads();
    int n = tid >> 2, c4 = (tid & 3) * 16;
    unsigned buf[8];
#pragma unroll
    for (int i = 0; i < 8; i++)
        buf[i] = f2bf(sT[c4 + 2 * i][n]) | (f2bf(sT[c4 + 2 * i + 1][n]) << 16);
    short* dst = xT + ((size_t)b * NTOK + n0 + n) * CIN + c0 + c4;
    ((uint4*)dst)[0] = make_uint4(buf[0], buf[1], buf[2], buf[3]);
    ((uint4*)dst)[1] = make_uint4(buf[4], buf[5], buf[6], buf[7]);
}

// ---------------------------------------------------------------------------
// QKV GEMM (MFMA, register double-buffered): rows o<1024 (q,k) -> fp32 qkf;
// rows >=1024 (v) -> bf16 vb [b][512][NTOK]. BM=64, BN=128, K=256.
// grid (18, 24, 2). launch_bounds(256,2): cap VGPR at 256 so the prefetch
// buffers stay in registers (at (256) default the compiler throttled to
// 56-80 VGPR and issued operand loads just-in-time -> latency-serialized).
// ---------------------------------------------------------------------------
__global__ __launch_bounds__(256, 2) void gemm_qkv(
    const short* __restrict__ A, const short* __restrict__ B,
    float* __restrict__ qkf, short* __restrict__ vb)
{
    const int K = CIN;
    int b = blockIdx.z;
    int o0 = blockIdx.y * 64;
    int n0 = blockIdx.x * 128;
    int tid = threadIdx.x, wv = tid >> 6, lane = tid & 63;
    int h = lane >> 5, l31 = lane & 31;

    const short* pa0 = A + (size_t)(o0 + l31) * K + h * 8;
    const short* pa1 = pa0 + (size_t)32 * K;
    const short* pb  = B + ((size_t)b * NTOK + n0 + wv * 32 + l31) * K + h * 8;

    bfrag a0[2], a1[2], bbf[2];
    a0[0] = *(const bfrag*)pa0;  a1[0] = *(const bfrag*)pa1;
    bbf[0] = *(const bfrag*)pb;
    pa0 += 16; pa1 += 16; pb += 16;

    f32x16 acc0, acc1;
#pragma unroll
    for (int r = 0; r < 16; r++) { acc0[r] = 0.f; acc1[r] = 0.f; }

#pragma unroll 2
    for (int it = 0; it < K / 16; it++) {
        int cur = it & 1, nxt = cur ^ 1;
        if (it < K / 16 - 1) {
            a0[nxt] = *(const bfrag*)pa0;
            a1[nxt] = *(const bfrag*)pa1;
            bbf[nxt] = *(const bfrag*)pb;
            pa0 += 16; pa1 += 16; pb += 16;
        }
        acc0 = __builtin_amdgcn_mfma_f32_32x32x16_bf16(a0[cur], bbf[cur], acc0, 0, 0, 0);
        acc1 = __builtin_amdgcn_mfma_f32_32x32x16_bf16(a1[cur], bbf[cur], acc1, 0, 0, 0);
    }

    int nn = n0 + wv * 32 + l31;
    if (o0 < 1024) {
        float* Q = qkf + (size_t)b * 1024 * NTOK;
#pragma unroll
        for (int r = 0; r < 16; r++) {
            int ml = (r & 3) + 8 * (r >> 2) + 4 * h;
            Q[(size_t)(o0 + ml) * NTOK + nn] = acc0[r];
            Q[(size_t)(o0 + 32 + ml) * NTOK + nn] = acc1[r];
        }
    } else {
        short* V = vb + (size_t)b * 512 * NTOK;
        int ov = o0 - 1024;
#pragma unroll
        for (int r = 0; r < 16; r++) {
            int ml = (r & 3) + 8 * (r >> 2) + 4 * h;
            V[(size_t)(ov + ml) * NTOK + nn] = (short)f2bf(acc0[r]);
            V[(size_t)(ov + 32 + ml) * NTOK + nn] = (short)f2bf(acc1[r]);
        }
    }
}

// ---------------------------------------------------------------------------
// Row inverse L2-norm over tokens for q,k rows (2 x 1024 rows).
// ---------------------------------------------------------------------------
__global__ __launch_bounds__(256) void rownorm(
    const float* __restrict__ qkf, float* __restrict__ invn)
{
    int row = blockIdx.x;              // 0..2047
    int b = row >> 10, o = row & 1023;
    const float* p = qkf + ((size_t)b * 1024 + o) * NTOK;
    int tid = threadIdx.x;
    float s = 0.f;
    for (int n = tid; n < NTOK; n += 256) { float v = p[n]; s += v * v; }
#pragma unroll
    for (int off = 32; off > 0; off >>= 1) s += __shfl_down(s, off, 64);
    __shared__ float ws[4];
    if ((tid & 63) == 0) ws[tid >> 6] = s;
    __syncthreads();
    if (tid == 0) {
        float tot = ws[0] + ws[1] + ws[2] + ws[3];
        invn[row] = 1.f / fmaxf(sqrtf(tot), 1e-12f);
    }
}

// ---------------------------------------------------------------------------
// Pack normalized q,k -> bf16 token-major qkt [sel][bh][n][64].
// q additionally scaled by log2(e) so attention uses exp2 directly.
// ---------------------------------------------------------------------------
__global__ __launch_bounds__(256) void pack_qk(
    const float* __restrict__ qkf, const float* __restrict__ invn,
    short* __restrict__ qkt)
{
    int n0 = blockIdx.x * 64;
    int bh = blockIdx.y;
    int sel = blockIdx.z;
    int b = bh >> 3, h = bh & 7;
    const float* src = qkf + ((size_t)b * 1024 + sel * 512 + h * 64) * NTOK;
    int base = b * 1024 + sel * 512 + h * 64;
    float extra = sel == 0 ? LOG2E : 1.f;

    __shared__ float sT[64][65];
    int tid = threadIdx.x, lane = tid & 63, wv = tid >> 6;
    for (int d = wv; d < 64; d += 4)
        sT[d][lane] = src[(size_t)d * NTOK + n0 + lane] * (invn[base + d] * extra);
    __syncthreads();

    int n = tid >> 2, c4 = (tid & 3) * 16;
    unsigned buf[8];
#pragma unroll
    for (int i = 0; i < 8; i++)
        buf[i] = f2bf(sT[c4 + 2 * i][n]) | (f2bf(sT[c4 + 2 * i + 1][n]) << 16);
    short* dst = qkt + (size_t)sel * ((size_t)16 * NTOK * 64)
                     + ((size_t)bh * NTOK + n0 + n) * 64 + c4;
    ((uint4*)dst)[0] = make_uint4(buf[0], buf[1], buf[2], buf[3]);
    ((uint4*)dst)[1] = make_uint4(buf[4], buf[5], buf[6], buf[7]);
}

// ---------------------------------------------------------------------------
// Barrier-free attention, register double-buffered K/V prefetch.
// Wave owns 32 q-rows x one m-half (msplit=2, 36 iters of 32 m).
// S^T = mfma(A=K, B=Q) -> per-lane row sums; P relayout = lane^32 half-swap.
// No max subtraction (L2-normed q,k bound |S|<=1). Direct stores per split.
// grid (18, 16 bh, 2 msplit). launch_bounds(256,2): see gemm_qkv note —
// the whole point of this round.
// ---------------------------------------------------------------------------
__global__ __launch_bounds__(256, 2) void attn_nb(
    const short* __restrict__ qkt,   // [2][16][2304][64] bf16 (q pre-scaled log2e)
    const short* __restrict__ vb,    // [2][512][2304] bf16
    float* __restrict__ Opart,       // [2 split][2][2304][512] fp32
    float* __restrict__ lsum)        // [2 split][16][2304] fp32
{
    int bh = blockIdx.y;
    int b = bh >> 3, hh = bh & 7;
    int tid = threadIdx.x, wv = tid >> 6, lane = tid & 63;
    int h = lane >> 5, l31 = lane & 31;
    int n0w = blockIdx.x * 128 + wv * 32;
    int ms = blockIdx.z;
    int mbase = ms * (NTOK / 2);

    const short* Qrow = qkt + ((size_t)bh * NTOK + n0w + l31) * 64 + h * 8;
    const short* kp = qkt + (size_t)16 * NTOK * 64
                    + ((size_t)bh * NTOK + mbase + l31) * 64 + h * 8;
    const short* vl = vb + ((size_t)b * 512 + hh * 64 + l31) * NTOK + mbase + h * 8;
    const short* vh2 = vl + (size_t)32 * NTOK;

    bfrag bQ[4];
#pragma unroll
    for (int i = 0; i < 4; i++) bQ[i] = *(const bfrag*)(Qrow + i * 16);

    // prime prefetch buffers (iter 0)
    bfrag kb[2][4], vbl[2][2], vbh[2][2];
#pragma unroll
    for (int i = 0; i < 4; i++) kb[0][i] = *(const bfrag*)(kp + i * 16);
    vbl[0][0] = *(const bfrag*)vl;  vbl[0][1] = *(const bfrag*)(vl + 16);
    vbh[0][0] = *(const bfrag*)vh2; vbh[0][1] = *(const bfrag*)(vh2 + 16);
    kp += 2048; vl += 32; vh2 += 32;

    f32x16 accLo, accHi;
#pragma unroll
    for (int r = 0; r < 16; r++) { accLo[r] = 0.f; accHi[r] = 0.f; }
    float ps0 = 0.f, ps1 = 0.f;

#pragma unroll 2
    for (int it = 0; it < 36; it++) {
        int cur = it & 1, nxt = cur ^ 1;
        if (it < 35) {                      // prefetch next m-tile
#pragma unroll
            for (int i = 0; i < 4; i++) kb[nxt][i] = *(const bfrag*)(kp + i * 16);
            vbl[nxt][0] = *(const bfrag*)vl;  vbl[nxt][1] = *(const bfrag*)(vl + 16);
            vbh[nxt][0] = *(const bfrag*)vh2; vbh[nxt][1] = *(const bfrag*)(vh2 + 16);
            kp += 2048; vl += 32; vh2 += 32;
        }
        // ---- S^T tile (32m x 32n): 4 MFMA over d
        f32x16 accS;
#pragma unroll
        for (int r = 0; r < 16; r++) accS[r] = 0.f;
#pragma unroll
        for (int i = 0; i < 4; i++)
            accS = __builtin_amdgcn_mfma_f32_32x32x16_bf16(kb[cur][i], bQ[i], accS, 0, 0, 0);
        // ---- P = 2^S, pack to bf16 (trunc, 1 v_perm/pair), sums from packed
        unsigned dw[8];
#pragma unroll
        for (int i = 0; i < 8; i++) {
            float plo = EXP2(accS[2 * i]);
            float phi = EXP2(accS[2 * i + 1]);
            dw[i] = pk_trunc(plo, phi);
            ps0 += __uint_as_float(dw[i] << 16);
            ps1 += __uint_as_float(dw[i] & 0xffff0000u);
        }
        // ---- half-swap -> A-operand frags (lane keeps its n = l31)
        unsigned sa0 = h ? dw[0] : dw[2], sb0 = h ? dw[1] : dw[3];
        unsigned sa1 = h ? dw[4] : dw[6], sb1 = h ? dw[5] : dw[7];
        unsigned ra0 = (unsigned)__shfl_xor((int)sa0, 32, 64);
        unsigned rb0 = (unsigned)__shfl_xor((int)sb0, 32, 64);
        unsigned ra1 = (unsigned)__shfl_xor((int)sa1, 32, 64);
        unsigned rb1 = (unsigned)__shfl_xor((int)sb1, 32, 64);
        union { bfrag f; unsigned u[4]; } P0, P1;
        P0.u[0] = h ? ra0 : dw[0];  P0.u[1] = h ? rb0 : dw[1];
        P0.u[2] = h ? dw[2] : ra0;  P0.u[3] = h ? dw[3] : rb0;
        P1.u[0] = h ? ra1 : dw[4];  P1.u[1] = h ? rb1 : dw[5];
        P1.u[2] = h ? dw[6] : ra1;  P1.u[3] = h ? dw[7] : rb1;
        // ---- O^T += P V
        accLo = __builtin_amdgcn_mfma_f32_32x32x16_bf16(P0.f, vbl[cur][0], accLo, 0, 0, 0);
        accLo = __builtin_amdgcn_mfma_f32_32x32x16_bf16(P1.f, vbl[cur][1], accLo, 0, 0, 0);
        accHi = __builtin_amdgcn_mfma_f32_32x32x16_bf16(P0.f, vbh[cur][0], accHi, 0, 0, 0);
        accHi = __builtin_amdgcn_mfma_f32_32x32x16_bf16(P1.f, vbh[cur][1], accHi, 0, 0, 0);
    }

    // ---- row sums: fold partner half, direct store (per-split, per-wave n's)
    float pst = ps0 + ps1;
    pst += __shfl_xor(pst, 32, 64);
    if (h == 0)
        lsum[((size_t)ms * 16 + bh) * NTOK + n0w + l31] = pst;

    // ---- O^T partial store (direct, no atomics)
    float* Ob = Opart + (size_t)ms * (2ull * NTOK * HID)
              + (size_t)b * NTOK * HID + hh * 64;
#pragma unroll
    for (int r = 0; r < 16; r++) {
        int n = n0w + (r & 3) + 8 * (r >> 2) + 4 * h;
        Ob[(size_t)n * HID + l31] = accLo[r];
        Ob[(size_t)n * HID + 32 + l31] = accHi[r];
    }
}

// ---------------------------------------------------------------------------
// Combine two m-splits, normalize, pack bf16 aoT [b][n][512]. 8 elems/thread.
// ---------------------------------------------------------------------------
__global__ __launch_bounds__(256) void combine(
    const float* __restrict__ Opart, const float* __restrict__ lsum,
    short* __restrict__ aoT)
{
    size_t e = ((size_t)blockIdx.x * 256 + threadIdx.x) * 8;
    int c = (int)(e & 511);
    size_t row = e >> 9;                 // b*2304 + n
    int b = (int)(row / NTOK), n = (int)(row - (size_t)b * NTOK);
    int hh = c >> 6;
    float l0 = lsum[(size_t)(b * 8 + hh) * NTOK + n];
    float l1 = lsum[(size_t)16 * NTOK + (size_t)(b * 8 + hh) * NTOK + n];
    float inv = 1.f / (l0 + l1);
    const float* P0 = Opart + e;
    const float* P1 = Opart + (size_t)2 * NTOK * HID + e;
    float4 a0 = ((const float4*)P0)[0], a1 = ((const float4*)P0)[1];
    float4 c0 = ((const float4*)P1)[0], c1 = ((const float4*)P1)[1];
    unsigned b0 = f2bf((a0.x + c0.x) * inv) | (f2bf((a0.y + c0.y) * inv) << 16);
    unsigned b1 = f2bf((a0.z + c0.z) * inv) | (f2bf((a0.w + c0.w) * inv) << 16);
    unsigned b2 = f2bf((a1.x + c1.x) * inv) | (f2bf((a1.y + c1.y) * inv) << 16);
    unsigned b3 = f2bf((a1.z + c1.z) * inv) | (f2bf((a1.w + c1.w) * inv) << 16);
    *((uint4*)(aoT + e)) = make_uint4(b0, b1, b2, b3);
}

// ---------------------------------------------------------------------------
// Proj GEMM (MFMA, double-buffered, direct store + bias). BM=64, BN=128,
// K=512. grid (18, 4, 2). y fully overwritten. launch_bounds(256,2): ditto.
// ---------------------------------------------------------------------------
__global__ __launch_bounds__(256, 2) void gemm_proj(
    const short* __restrict__ A, const short* __restrict__ B,
    const float* __restrict__ bias, float* __restrict__ y)
{
    const int K = HID;
    int b = blockIdx.z;
    int o0 = blockIdx.y * 64;
    int n0 = blockIdx.x * 128;
    int tid = threadIdx.x, wv = tid >> 6, lane = tid & 63;
    int h = lane >> 5, l31 = lane & 31;

    const short* pa0 = A + (size_t)(o0 + l31) * K + h * 8;
    const short* pa1 = pa0 + (size_t)32 * K;
    const short* pb  = B + ((size_t)b * NTOK + n0 + wv * 32 + l31) * K + h * 8;

    bfrag a0[2], a1[2], bbf[2];
    a0[0] = *(const bfrag*)pa0;  a1[0] = *(const bfrag*)pa1;
    bbf[0] = *(const bfrag*)pb;
    pa0 += 16; pa1 += 16; pb += 16;

    f32x16 acc0, acc1;
#pragma unroll
    for (int r = 0; r < 16; r++) { acc0[r] = 0.f; acc1[r] = 0.f; }

#pragma unroll 2
    for (int it = 0; it < K / 16; it++) {
        int cur = it & 1, nxt = cur ^ 1;
        if (it < K / 16 - 1) {
            a0[nxt] = *(const bfrag*)pa0;
            a1[nxt] = *(const bfrag*)pa1;
            bbf[nxt] = *(const bfrag*)pb;
            pa0 += 16; pa1 += 16; pb += 16;
        }
        acc0 = __builtin_amdgcn_mfma_f32_32x32x16_bf16(a0[cur], bbf[cur], acc0, 0, 0, 0);
        acc1 = __builtin_amdgcn_mfma_f32_32x32x16_bf16(a1[cur], bbf[cur], acc1, 0, 0, 0);
    }

    int nn = n0 + wv * 32 + l31;
#pragma unroll
    for (int r = 0; r < 16; r++) {
        int ml = (r & 3) + 8 * (r >> 2) + 4 * h;
        y[((size_t)b * CIN + o0 + ml) * NTOK + nn] = acc0[r] + bias[o0 + ml];
        y[((size_t)b * CIN + o0 + 32 + ml) * NTOK + nn] = acc1[r] + bias[o0 + 32 + ml];
    }
}

// ---------------------------------------------------------------------------
// Workspace (<= 36,446,208 B of 37,748,736):
//   [0, 18,874,368)           qkf fp32 [2][1024][2304]   (k3 -> k5)
//       then Opart fp32 [2 split][2][2304][512]          (k6 -> k7, exact fit)
//   [18,874,368, 23,592,960)  vb bf16 [2][512][2304]     (k3 -> k6)
//   [23,592,960, 33,030,144)  qkt bf16 [2][16][2304][64] (k5 -> k6)
//       then aoT bf16 [2][2304][512] at 23,592,960       (k7 -> k8)
//   [33,030,144, 33,325,056)  lsum fp32 [2][16][2304]    (k6 -> k7, over dead xT)
//   [33,030,144, 35,389,440)  xT bf16                     (k2 -> k3, dead at k6)
//   [35,389,440, 36,175,872)  wqb bf16
//   [36,175,872, 36,438,016)  wpb bf16
//   [36,438,016, 36,446,208)  invn fp32 [2048]
// ---------------------------------------------------------------------------
extern "C" void kernel_launch(void* const* d_in, const int* in_sizes, int n_in,
                              void* d_out, int out_size, void* d_ws, size_t ws_size,
                              hipStream_t stream)
{
    const float* x      = (const float*)d_in[0];
    const float* w_qkv  = (const float*)d_in[1];
    const float* w_proj = (const float*)d_in[2];
    const float* b_proj = (const float*)d_in[3];
    float* y = (float*)d_out;

    float* qkf   = (float*)d_ws;
    float* Opart = (float*)d_ws;
    short* vb    = (short*)((char*)d_ws + 18874368);
    short* qkt   = (short*)((char*)d_ws + 23592960);
    short* aoT   = (short*)((char*)d_ws + 23592960);
    float* lsum  = (float*)((char*)d_ws + 33030144);
    short* xT    = (short*)((char*)d_ws + 33030144);
    short* wqb   = (short*)((char*)d_ws + 35389440);
    short* wpb   = (short*)((char*)d_ws + 36175872);
    float* invn  = (float*)((char*)d_ws + 36438016);

    // k1: pack both weights
    pack_weights<<<(1536 * 256 + 256 * 512) / 8 / 256, 256, 0, stream>>>(
        w_qkv, wqb, w_proj, wpb);
    // k2: transpose-pack x
    pack_xT<<<dim3(NTOK / 64, CIN / 64, BATCH), 256, 0, stream>>>(x, xT);
    // k3: QKV GEMM (q,k fp32; v straight to bf16)
    gemm_qkv<<<dim3(NTOK / 128, 1536 / 64, BATCH), 256, 0, stream>>>(
        wqb, xT, qkf, vb);
    // k4: inverse row norms
    rownorm<<<2048, 256, 0, stream>>>(qkf, invn);
    // k5: pack normalized q (x log2e), k -> token-major bf16
    pack_qk<<<dim3(NTOK / 64, BATCH * NH, 2), 256, 0, stream>>>(qkf, invn, qkt);
    // k6: barrier-free attention, msplit=2, double-buffered (qkf dead -> Opart)
    attn_nb<<<dim3(NTOK / 128, BATCH * NH, 2), 256, 0, stream>>>(
        qkt, vb, Opart, lsum);
    // k7: combine splits -> aoT bf16 (over dead qkt)
    combine<<<(BATCH * NTOK * HID / 8) / 256, 256, 0, stream>>>(Opart, lsum, aoT);
    // k8: proj GEMM, direct store + bias
    gemm_proj<<<dim3(NTOK / 128, CIN / 64, BATCH), 256, 0, stream>>>(
        wpb, aoT, b_proj, y);
}

// Round 7
// 196.199 us; speedup vs baseline: 1.1396x; 1.1396x over previous
//
#include <hip/hip_runtime.h>
#include <math.h>

#define NTOK 2304      // 48*48 tokens
#define BATCH 2
#define CIN 256
#define HID 512        // 8 heads * 64
#define NH 8
#define LOG2E 1.44269504088896340736f

typedef __attribute__((ext_vector_type(8))) short bfrag;    // 8 bf16 (4 VGPRs)
typedef __attribute__((ext_vector_type(16))) float f32x16;  // MFMA 32x32 accumulator

#if __has_builtin(__builtin_amdgcn_exp2f)
#define EXP2(x) __builtin_amdgcn_exp2f(x)
#else
#define EXP2(x) exp2f(x)
#endif

// fp32 -> bf16 (RNE)
__device__ __forceinline__ unsigned f2bf(float f) {
    unsigned u = __float_as_uint(f);
    u += 0x7FFF + ((u >> 16) & 1);
    return u >> 16;
}

// pack trunc(hi(b)) , trunc(hi(a)) -> one dword {bf16(b):bf16(a)} in 1 v_perm
__device__ __forceinline__ unsigned pk_trunc(float a, float b) {
    return __builtin_amdgcn_perm(__float_as_uint(b), __float_as_uint(a), 0x07060302u);
}

// exp2 + bf16-pack + lane^32 half-swap: accS (S^T quadrant, C-layout) ->
// two A-operand P frags; accumulates this lane's partial row sums.
__device__ __forceinline__ void softmax_frag(
    const f32x16& accS, int h, float& ps0, float& ps1, bfrag& P0, bfrag& P1)
{
    unsigned dw[8];
#pragma unroll
    for (int i = 0; i < 8; i++) {
        float plo = EXP2(accS[2 * i]);
        float phi = EXP2(accS[2 * i + 1]);
        dw[i] = pk_trunc(plo, phi);
        ps0 += __uint_as_float(dw[i] << 16);
        ps1 += __uint_as_float(dw[i] & 0xffff0000u);
    }
    unsigned sa0 = h ? dw[0] : dw[2], sb0 = h ? dw[1] : dw[3];
    unsigned sa1 = h ? dw[4] : dw[6], sb1 = h ? dw[5] : dw[7];
    unsigned ra0 = (unsigned)__shfl_xor((int)sa0, 32, 64);
    unsigned rb0 = (unsigned)__shfl_xor((int)sb0, 32, 64);
    unsigned ra1 = (unsigned)__shfl_xor((int)sa1, 32, 64);
    unsigned rb1 = (unsigned)__shfl_xor((int)sb1, 32, 64);
    union { bfrag f; unsigned u[4]; } U0, U1;
    U0.u[0] = h ? ra0 : dw[0];  U0.u[1] = h ? rb0 : dw[1];
    U0.u[2] = h ? dw[2] : ra0;  U0.u[3] = h ? dw[3] : rb0;
    U1.u[0] = h ? ra1 : dw[4];  U1.u[1] = h ? rb1 : dw[5];
    U1.u[2] = h ? dw[6] : ra1;  U1.u[3] = h ? dw[7] : rb1;
    P0 = U0.f; P1 = U1.f;
}

// ---------------------------------------------------------------------------
// Pack both weight matrices fp32 -> bf16 in one dispatch.
// ---------------------------------------------------------------------------
__global__ __launch_bounds__(256) void pack_weights(
    const float* __restrict__ wq, short* __restrict__ wqb,
    const float* __restrict__ wp, short* __restrict__ wpb)
{
    int e = (blockIdx.x * 256 + threadIdx.x) * 8;
    const int NQ = 1536 * 256;
    const float* src; short* dst;
    if (e < NQ) { src = wq + e; dst = wqb + e; }
    else        { src = wp + (e - NQ); dst = wpb + (e - NQ); }
    float4 v0 = ((const float4*)src)[0];
    float4 v1 = ((const float4*)src)[1];
    unsigned b0 = f2bf(v0.x) | (f2bf(v0.y) << 16);
    unsigned b1 = f2bf(v0.z) | (f2bf(v0.w) << 16);
    unsigned b2 = f2bf(v1.x) | (f2bf(v1.y) << 16);
    unsigned b3 = f2bf(v1.z) | (f2bf(v1.w) << 16);
    *((uint4*)dst) = make_uint4(b0, b1, b2, b3);
}

// ---------------------------------------------------------------------------
// Transpose-pack x: fp32 [b][256][2304] -> bf16 xT [b][2304][256]
// ---------------------------------------------------------------------------
__global__ __launch_bounds__(256) void pack_xT(
    const float* __restrict__ x, short* __restrict__ xT)
{
    int n0 = blockIdx.x * 64, c0 = blockIdx.y * 64, b = blockIdx.z;
    __shared__ float sT[64][65];
    int tid = threadIdx.x, lane = tid & 63, wv = tid >> 6;
    for (int c = wv; c < 64; c += 4)
        sT[c][lane] = x[((size_t)b * CIN + c0 + c) * NTOK + n0 + lane];
    __syncthreads();
    int n = tid >> 2, c4 = (tid & 3) * 16;
    unsigned buf[8];
#pragma unroll
    for (int i = 0; i < 8; i++)
        buf[i] = f2bf(sT[c4 + 2 * i][n]) | (f2bf(sT[c4 + 2 * i + 1][n]) << 16);
    short* dst = xT + ((size_t)b * NTOK + n0 + n) * CIN + c0 + c4;
    ((uint4*)dst)[0] = make_uint4(buf[0], buf[1], buf[2], buf[3]);
    ((uint4*)dst)[1] = make_uint4(buf[4], buf[5], buf[6], buf[7]);
}

// ---------------------------------------------------------------------------
// QKV GEMM (MFMA): BM=128, BN=128, K=256. rows o<1024 (q,k) -> fp32 qkf;
// rows >=1024 (v) -> bf16 vb [b][512][NTOK]. grid (18, 12, 2).
// 4 MFMA + 5 loads per k-chunk (A-tile reused 128-wide), unroll 2.
// ---------------------------------------------------------------------------
__global__ __launch_bounds__(256, 2) void gemm_qkv(
    const short* __restrict__ A, const short* __restrict__ B,
    float* __restrict__ qkf, short* __restrict__ vb)
{
    const int K = CIN;
    int b = blockIdx.z;
    int o0 = blockIdx.y * 128;
    int n0 = blockIdx.x * 128;
    int tid = threadIdx.x, wv = tid >> 6, lane = tid & 63;
    int h = lane >> 5, l31 = lane & 31;

    const short* pa = A + (size_t)(o0 + l31) * K + h * 8;
    const short* pb = B + ((size_t)b * NTOK + n0 + wv * 32 + l31) * K + h * 8;

    f32x16 acc[4];
#pragma unroll
    for (int rb = 0; rb < 4; rb++)
#pragma unroll
        for (int r = 0; r < 16; r++) acc[rb][r] = 0.f;

#pragma unroll 2
    for (int kt = 0; kt < K; kt += 16) {
        bfrag a0 = *(const bfrag*)(pa + kt);
        bfrag a1 = *(const bfrag*)(pa + (size_t)32 * K + kt);
        bfrag a2 = *(const bfrag*)(pa + (size_t)64 * K + kt);
        bfrag a3 = *(const bfrag*)(pa + (size_t)96 * K + kt);
        bfrag bb = *(const bfrag*)(pb + kt);
        acc[0] = __builtin_amdgcn_mfma_f32_32x32x16_bf16(a0, bb, acc[0], 0, 0, 0);
        acc[1] = __builtin_amdgcn_mfma_f32_32x32x16_bf16(a1, bb, acc[1], 0, 0, 0);
        acc[2] = __builtin_amdgcn_mfma_f32_32x32x16_bf16(a2, bb, acc[2], 0, 0, 0);
        acc[3] = __builtin_amdgcn_mfma_f32_32x32x16_bf16(a3, bb, acc[3], 0, 0, 0);
    }

    int nn = n0 + wv * 32 + l31;
    if (o0 < 1024) {
        float* Q = qkf + (size_t)b * 1024 * NTOK;
#pragma unroll
        for (int rb = 0; rb < 4; rb++)
#pragma unroll
            for (int r = 0; r < 16; r++) {
                int ml = (r & 3) + 8 * (r >> 2) + 4 * h;
                Q[(size_t)(o0 + rb * 32 + ml) * NTOK + nn] = acc[rb][r];
            }
    } else {
        short* V = vb + (size_t)b * 512 * NTOK;
        int ov = o0 - 1024;
#pragma unroll
        for (int rb = 0; rb < 4; rb++)
#pragma unroll
            for (int r = 0; r < 16; r++) {
                int ml = (r & 3) + 8 * (r >> 2) + 4 * h;
                V[(size_t)(ov + rb * 32 + ml) * NTOK + nn] = (short)f2bf(acc[rb][r]);
            }
    }
}

// ---------------------------------------------------------------------------
// Row inverse L2-norm over tokens for q,k rows (2 x 1024 rows).
// ---------------------------------------------------------------------------
__global__ __launch_bounds__(256) void rownorm(
    const float* __restrict__ qkf, float* __restrict__ invn)
{
    int row = blockIdx.x;              // 0..2047
    int b = row >> 10, o = row & 1023;
    const float* p = qkf + ((size_t)b * 1024 + o) * NTOK;
    int tid = threadIdx.x;
    float s = 0.f;
    for (int n = tid; n < NTOK; n += 256) { float v = p[n]; s += v * v; }
#pragma unroll
    for (int off = 32; off > 0; off >>= 1) s += __shfl_down(s, off, 64);
    __shared__ float ws[4];
    if ((tid & 63) == 0) ws[tid >> 6] = s;
    __syncthreads();
    if (tid == 0) {
        float tot = ws[0] + ws[1] + ws[2] + ws[3];
        invn[row] = 1.f / fmaxf(sqrtf(tot), 1e-12f);
    }
}

// ---------------------------------------------------------------------------
// Pack normalized q,k -> bf16 token-major qkt [sel][bh][n][64].
// q additionally scaled by log2(e) so attention uses exp2 directly.
// ---------------------------------------------------------------------------
__global__ __launch_bounds__(256) void pack_qk(
    const float* __restrict__ qkf, const float* __restrict__ invn,
    short* __restrict__ qkt)
{
    int n0 = blockIdx.x * 64;
    int bh = blockIdx.y;
    int sel = blockIdx.z;
    int b = bh >> 3, h = bh & 7;
    const float* src = qkf + ((size_t)b * 1024 + sel * 512 + h * 64) * NTOK;
    int base = b * 1024 + sel * 512 + h * 64;
    float extra = sel == 0 ? LOG2E : 1.f;

    __shared__ float sT[64][65];
    int tid = threadIdx.x, lane = tid & 63, wv = tid >> 6;
    for (int d = wv; d < 64; d += 4)
        sT[d][lane] = src[(size_t)d * NTOK + n0 + lane] * (invn[base + d] * extra);
    __syncthreads();

    int n = tid >> 2, c4 = (tid & 3) * 16;
    unsigned buf[8];
#pragma unroll
    for (int i = 0; i < 8; i++)
        buf[i] = f2bf(sT[c4 + 2 * i][n]) | (f2bf(sT[c4 + 2 * i + 1][n]) << 16);
    short* dst = qkt + (size_t)sel * ((size_t)16 * NTOK * 64)
                     + ((size_t)bh * NTOK + n0 + n) * 64 + c4;
    ((uint4*)dst)[0] = make_uint4(buf[0], buf[1], buf[2], buf[3]);
    ((uint4*)dst)[1] = make_uint4(buf[4], buf[5], buf[6], buf[7]);
}

// ---------------------------------------------------------------------------
// Barrier-free attention, fat blocks + XCD locality.
// 1-D grid 288: group = bid & 31 -> (bh, ms); ntile = bid >> 5 (9 x 256 n).
// Sharers of one (bh,ms) K/V-set have ids differing by 32 (= 0 mod 8) ->
// same XCD under round-robin dispatch -> K/V hot set (~1.2 MB) L2-resident.
// Wave owns two 32-n groups (nb0, nb0+128) sharing the same K/V loads:
// 8 loads serve 16 MFMAs + 32 exp2 per iter. All loads issued at iter top.
// ---------------------------------------------------------------------------
__global__ __launch_bounds__(256, 2) void attn_nb(
    const short* __restrict__ qkt,   // [2][16][2304][64] bf16 (q pre-scaled log2e)
    const short* __restrict__ vb,    // [2][512][2304] bf16
    float* __restrict__ Opart,       // [2 split][2][2304][512] fp32
    float* __restrict__ lsum)        // [2 split][16][2304] fp32
{
    int bid = blockIdx.x;
    int g = bid & 31;
    int bh = g >> 1, ms = g & 1;
    int ntile = bid >> 5;
    int b = bh >> 3, hh = bh & 7;
    int tid = threadIdx.x, wv = tid >> 6, lane = tid & 63;
    int h = lane >> 5, l31 = lane & 31;
    int nb0 = ntile * 256 + wv * 32;
    int nb1 = nb0 + 128;
    int mbase = ms * (NTOK / 2);

    const short* Qt = qkt + (size_t)bh * NTOK * 64;
    const short* kp = qkt + (size_t)16 * NTOK * 64
                    + ((size_t)bh * NTOK + mbase + l31) * 64 + h * 8;
    const short* vl = vb + ((size_t)b * 512 + hh * 64 + l31) * NTOK + mbase + h * 8;
    const short* vh2 = vl + (size_t)32 * NTOK;

    bfrag bQ0[4], bQ1[4];
    {
        const short* q0 = Qt + (size_t)(nb0 + l31) * 64 + h * 8;
        const short* q1 = Qt + (size_t)(nb1 + l31) * 64 + h * 8;
#pragma unroll
        for (int i = 0; i < 4; i++) {
            bQ0[i] = *(const bfrag*)(q0 + i * 16);
            bQ1[i] = *(const bfrag*)(q1 + i * 16);
        }
    }

    f32x16 aL0, aH0, aL1, aH1;
#pragma unroll
    for (int r = 0; r < 16; r++) { aL0[r] = 0.f; aH0[r] = 0.f; aL1[r] = 0.f; aH1[r] = 0.f; }
    float s00 = 0.f, s01 = 0.f, s10 = 0.f, s11 = 0.f;

#pragma unroll 2
    for (int it = 0; it < 36; it++) {
        // ---- all 8 operand loads up front: one drain per iteration
        bfrag k0 = *(const bfrag*)(kp);
        bfrag k1 = *(const bfrag*)(kp + 16);
        bfrag k2 = *(const bfrag*)(kp + 32);
        bfrag k3 = *(const bfrag*)(kp + 48);
        bfrag v00 = *(const bfrag*)(vl);
        bfrag v01 = *(const bfrag*)(vl + 16);
        bfrag v10 = *(const bfrag*)(vh2);
        bfrag v11 = *(const bfrag*)(vh2 + 16);
        kp += 2048; vl += 32; vh2 += 32;

        // ---- S^T for group 0, softmax, then group 1 (accS regs reused)
        bfrag P00, P01, P10, P11;
        {
            f32x16 accS;
#pragma unroll
            for (int r = 0; r < 16; r++) accS[r] = 0.f;
            accS = __builtin_amdgcn_mfma_f32_32x32x16_bf16(k0, bQ0[0], accS, 0, 0, 0);
            accS = __builtin_amdgcn_mfma_f32_32x32x16_bf16(k1, bQ0[1], accS, 0, 0, 0);
            accS = __builtin_amdgcn_mfma_f32_32x32x16_bf16(k2, bQ0[2], accS, 0, 0, 0);
            accS = __builtin_amdgcn_mfma_f32_32x32x16_bf16(k3, bQ0[3], accS, 0, 0, 0);
            softmax_frag(accS, h, s00, s01, P00, P01);
        }
        {
            f32x16 accS;
#pragma unroll
            for (int r = 0; r < 16; r++) accS[r] = 0.f;
            accS = __builtin_amdgcn_mfma_f32_32x32x16_bf16(k0, bQ1[0], accS, 0, 0, 0);
            accS = __builtin_amdgcn_mfma_f32_32x32x16_bf16(k1, bQ1[1], accS, 0, 0, 0);
            accS = __builtin_amdgcn_mfma_f32_32x32x16_bf16(k2, bQ1[2], accS, 0, 0, 0);
            accS = __builtin_amdgcn_mfma_f32_32x32x16_bf16(k3, bQ1[3], accS, 0, 0, 0);
            softmax_frag(accS, h, s10, s11, P10, P11);
        }
        // ---- O^T += P V (V frags shared across both n-groups)
        aL0 = __builtin_amdgcn_mfma_f32_32x32x16_bf16(P00, v00, aL0, 0, 0, 0);
        aL0 = __builtin_amdgcn_mfma_f32_32x32x16_bf16(P01, v01, aL0, 0, 0, 0);
        aH0 = __builtin_amdgcn_mfma_f32_32x32x16_bf16(P00, v10, aH0, 0, 0, 0);
        aH0 = __builtin_amdgcn_mfma_f32_32x32x16_bf16(P01, v11, aH0, 0, 0, 0);
        aL1 = __builtin_amdgcn_mfma_f32_32x32x16_bf16(P10, v00, aL1, 0, 0, 0);
        aL1 = __builtin_amdgcn_mfma_f32_32x32x16_bf16(P11, v01, aL1, 0, 0, 0);
        aH1 = __builtin_amdgcn_mfma_f32_32x32x16_bf16(P10, v10, aH1, 0, 0, 0);
        aH1 = __builtin_amdgcn_mfma_f32_32x32x16_bf16(P11, v11, aH1, 0, 0, 0);
    }

    // ---- row sums: fold partner half, direct store
    float p0 = s00 + s01;
    p0 += __shfl_xor(p0, 32, 64);
    float p1 = s10 + s11;
    p1 += __shfl_xor(p1, 32, 64);
    if (h == 0) {
        lsum[((size_t)ms * 16 + bh) * NTOK + nb0 + l31] = p0;
        lsum[((size_t)ms * 16 + bh) * NTOK + nb1 + l31] = p1;
    }

    // ---- O^T partial stores
    float* Ob = Opart + (size_t)ms * (2ull * NTOK * HID)
              + (size_t)b * NTOK * HID + hh * 64;
#pragma unroll
    for (int r = 0; r < 16; r++) {
        int ml = (r & 3) + 8 * (r >> 2) + 4 * h;
        Ob[(size_t)(nb0 + ml) * HID + l31] = aL0[r];
        Ob[(size_t)(nb0 + ml) * HID + 32 + l31] = aH0[r];
        Ob[(size_t)(nb1 + ml) * HID + l31] = aL1[r];
        Ob[(size_t)(nb1 + ml) * HID + 32 + l31] = aH1[r];
    }
}

// ---------------------------------------------------------------------------
// Combine two m-splits, normalize, pack bf16 aoT [b][n][512]. 8 elems/thread.
// ---------------------------------------------------------------------------
__global__ __launch_bounds__(256) void combine(
    const float* __restrict__ Opart, const float* __restrict__ lsum,
    short* __restrict__ aoT)
{
    size_t e = ((size_t)blockIdx.x * 256 + threadIdx.x) * 8;
    int c = (int)(e & 511);
    size_t row = e >> 9;                 // b*2304 + n
    int b = (int)(row / NTOK), n = (int)(row - (size_t)b * NTOK);
    int hh = c >> 6;
    float l0 = lsum[(size_t)(b * 8 + hh) * NTOK + n];
    float l1 = lsum[(size_t)16 * NTOK + (size_t)(b * 8 + hh) * NTOK + n];
    float inv = 1.f / (l0 + l1);
    const float* P0 = Opart + e;
    const float* P1 = Opart + (size_t)2 * NTOK * HID + e;
    float4 a0 = ((const float4*)P0)[0], a1 = ((const float4*)P0)[1];
    float4 c0 = ((const float4*)P1)[0], c1 = ((const float4*)P1)[1];
    unsigned b0 = f2bf((a0.x + c0.x) * inv) | (f2bf((a0.y + c0.y) * inv) << 16);
    unsigned b1 = f2bf((a0.z + c0.z) * inv) | (f2bf((a0.w + c0.w) * inv) << 16);
    unsigned b2 = f2bf((a1.x + c1.x) * inv) | (f2bf((a1.y + c1.y) * inv) << 16);
    unsigned b3 = f2bf((a1.z + c1.z) * inv) | (f2bf((a1.w + c1.w) * inv) << 16);
    *((uint4*)(aoT + e)) = make_uint4(b0, b1, b2, b3);
}

// ---------------------------------------------------------------------------
// Proj GEMM (MFMA, direct store + bias). BM=64, BN=128, K=512.
// grid (18, 4, 2). unroll 4: 12 loads in flight per body.
// ---------------------------------------------------------------------------
__global__ __launch_bounds__(256, 2) void gemm_proj(
    const short* __restrict__ A, const short* __restrict__ B,
    const float* __restrict__ bias, float* __restrict__ y)
{
    const int K = HID;
    int b = blockIdx.z;
    int o0 = blockIdx.y * 64;
    int n0 = blockIdx.x * 128;
    int tid = threadIdx.x, wv = tid >> 6, lane = tid & 63;
    int h = lane >> 5, l31 = lane & 31;

    const short* pa0 = A + (size_t)(o0 + l31) * K + h * 8;
    const short* pa1 = pa0 + (size_t)32 * K;
    const short* pb  = B + ((size_t)b * NTOK + n0 + wv * 32 + l31) * K + h * 8;

    f32x16 acc0, acc1;
#pragma unroll
    for (int r = 0; r < 16; r++) { acc0[r] = 0.f; acc1[r] = 0.f; }

#pragma unroll 4
    for (int kt = 0; kt < K; kt += 16) {
        bfrag a0 = *(const bfrag*)(pa0 + kt);
        bfrag a1 = *(const bfrag*)(pa1 + kt);
        bfrag bb = *(const bfrag*)(pb + kt);
        acc0 = __builtin_amdgcn_mfma_f32_32x32x16_bf16(a0, bb, acc0, 0, 0, 0);
        acc1 = __builtin_amdgcn_mfma_f32_32x32x16_bf16(a1, bb, acc1, 0, 0, 0);
    }

    int nn = n0 + wv * 32 + l31;
#pragma unroll
    for (int r = 0; r < 16; r++) {
        int ml = (r & 3) + 8 * (r >> 2) + 4 * h;
        y[((size_t)b * CIN + o0 + ml) * NTOK + nn] = acc0[r] + bias[o0 + ml];
        y[((size_t)b * CIN + o0 + 32 + ml) * NTOK + nn] = acc1[r] + bias[o0 + 32 + ml];
    }
}

// ---------------------------------------------------------------------------
// Workspace (<= 36,446,208 B of 37,748,736):
//   [0, 18,874,368)           qkf fp32 [2][1024][2304]   (k3 -> k5)
//       then Opart fp32 [2 split][2][2304][512]          (k6 -> k7, exact fit)
//   [18,874,368, 23,592,960)  vb bf16 [2][512][2304]     (k3 -> k6)
//   [23,592,960, 33,030,144)  qkt bf16 [2][16][2304][64] (k5 -> k6)
//       then aoT bf16 [2][2304][512] at 23,592,960       (k7 -> k8)
//   [33,030,144, 33,325,056)  lsum fp32 [2][16][2304]    (k6 -> k7, over dead xT)
//   [33,030,144, 35,389,440)  xT bf16                     (k2 -> k3, dead at k6)
//   [35,389,440, 36,175,872)  wqb bf16
//   [36,175,872, 36,438,016)  wpb bf16
//   [36,438,016, 36,446,208)  invn fp32 [2048]
// ---------------------------------------------------------------------------
extern "C" void kernel_launch(void* const* d_in, const int* in_sizes, int n_in,
                              void* d_out, int out_size, void* d_ws, size_t ws_size,
                              hipStream_t stream)
{
    const float* x      = (const float*)d_in[0];
    const float* w_qkv  = (const float*)d_in[1];
    const float* w_proj = (const float*)d_in[2];
    const float* b_proj = (const float*)d_in[3];
    float* y = (float*)d_out;

    float* qkf   = (float*)d_ws;
    float* Opart = (float*)d_ws;
    short* vb    = (short*)((char*)d_ws + 18874368);
    short* qkt   = (short*)((char*)d_ws + 23592960);
    short* aoT   = (short*)((char*)d_ws + 23592960);
    float* lsum  = (float*)((char*)d_ws + 33030144);
    short* xT    = (short*)((char*)d_ws + 33030144);
    short* wqb   = (short*)((char*)d_ws + 35389440);
    short* wpb   = (short*)((char*)d_ws + 36175872);
    float* invn  = (float*)((char*)d_ws + 36438016);

    // k1: pack both weights
    pack_weights<<<(1536 * 256 + 256 * 512) / 8 / 256, 256, 0, stream>>>(
        w_qkv, wqb, w_proj, wpb);
    // k2: transpose-pack x
    pack_xT<<<dim3(NTOK / 64, CIN / 64, BATCH), 256, 0, stream>>>(x, xT);
    // k3: QKV GEMM, BM=128 (q,k fp32; v straight to bf16)
    gemm_qkv<<<dim3(NTOK / 128, 1536 / 128, BATCH), 256, 0, stream>>>(
        wqb, xT, qkf, vb);
    // k4: inverse row norms
    rownorm<<<2048, 256, 0, stream>>>(qkf, invn);
    // k5: pack normalized q (x log2e), k -> token-major bf16
    pack_qk<<<dim3(NTOK / 64, BATCH * NH, 2), 256, 0, stream>>>(qkf, invn, qkt);
    // k6: attention — 288 fat blocks, XCD-swizzled 1-D grid
    attn_nb<<<288, 256, 0, stream>>>(qkt, vb, Opart, lsum);
    // k7: combine splits -> aoT bf16 (over dead qkt)
    combine<<<(BATCH * NTOK * HID / 8) / 256, 256, 0, stream>>>(Opart, lsum, aoT);
    // k8: proj GEMM, direct store + bias
    gemm_proj<<<dim3(NTOK / 128, CIN / 64, BATCH), 256, 0, stream>>>(
        wpb, aoT, b_proj, y);
}